// Round 11
// baseline (364.458 us; speedup 1.0000x reference)
//
#include <hip/hip_runtime.h>
#include <hip/hip_bf16.h>

// Problem constants
#define C_DIM  1024
#define NHEAD  16
#define DHEAD  64
#define T_LEN  2048
#define B_SZ   4
#define M_ROWS (B_SZ * T_LEN)   // 8192
#define QKV_N  (3 * C_DIM)      // 3072

typedef __bf16 bf16x8 __attribute__((ext_vector_type(8)));
typedef float  f32x4  __attribute__((ext_vector_type(4)));
typedef unsigned short ushort8_t __attribute__((ext_vector_type(8)));
typedef unsigned int   uint4_t   __attribute__((ext_vector_type(4)));

__device__ __forceinline__ unsigned short f2bf(float f) {
    union { float f; unsigned int u; } v; v.f = f;
    unsigned int r = v.u + 0x7FFFu + ((v.u >> 16) & 1u);
    return (unsigned short)(r >> 16);
}

__device__ __forceinline__ bf16x8 as_bf16x8(ushort8_t u) {
    return __builtin_bit_cast(bf16x8, u);
}

__device__ __forceinline__ f32x4 mfma16(bf16x8 a, bf16x8 b, f32x4 c) {
    return __builtin_amdgcn_mfma_f32_16x16x32_bf16(a, b, c, 0, 0, 0);
}

// async global->LDS, 16B per lane, dest = base + lane*16
#define GLL16(gsrc, ldst) __builtin_amdgcn_global_load_lds( \
    (const __attribute__((address_space(1))) void*)(gsrc),  \
    (__attribute__((address_space(3))) void*)(ldst), 16, 0, 0)

// bijective XCD-chunked remap (m204)
__device__ __forceinline__ int xcd_remap(int id, int nwg) {
    const int q = nwg >> 3, r = nwg & 7;
    const int xcd = id & 7, off = id >> 3;
    return (xcd < r) ? (xcd * (q + 1) + off) : (r * (q + 1) + (xcd - r) * q + off);
}

// ---------------- fp32 -> bf16 elementwise convert (vectorized) ----------------
__global__ void k_convert(const float* __restrict__ in, unsigned short* __restrict__ out, int n4) {
    int i = blockIdx.x * blockDim.x + threadIdx.x;
    if (i >= n4) return;
    const float4 v = ((const float4*)in)[i];
    unsigned int lo = (unsigned int)f2bf(v.x) | ((unsigned int)f2bf(v.y) << 16);
    unsigned int hi = (unsigned int)f2bf(v.z) | ((unsigned int)f2bf(v.w) << 16);
    ((uint2*)out)[i] = make_uint2(lo, hi);
}

// ---------------- fp32 [K][N] -> bf16 [N][K] tiled transpose ----------------
__global__ void k_transpose_bf16(const float* __restrict__ w, unsigned short* __restrict__ wT,
                                 int K, int N) {
    __shared__ float tile[32][33];
    const int n0 = blockIdx.x * 32, k0 = blockIdx.y * 32;
    const int tx = threadIdx.x, ty = threadIdx.y;  // 32 x 8
    for (int i = 0; i < 32; i += 8)
        tile[ty + i][tx] = w[(size_t)(k0 + ty + i) * N + (n0 + tx)];
    __syncthreads();
    for (int i = 0; i < 32; i += 8)
        wT[(size_t)(n0 + ty + i) * K + (k0 + tx)] = f2bf(tile[tx][ty + i]);
}

// ---------------- V -> V^T global pre-transpose (fallback if ws too small) ----------------
__global__ void k_transpose_v(const unsigned short* __restrict__ qkv,
                              unsigned short* __restrict__ vtg) {
    __shared__ unsigned short tile[32][33];
    const int tt = blockIdx.x;
    const int dy = blockIdx.y;
    const int bh = dy >> 1, dtile = dy & 1;
    const int b = bh >> 4, h = bh & 15;
    const int t0 = tt * 32, d0 = dtile * 32;
    const int tx = threadIdx.x, ty = threadIdx.y;  // 32 x 8
    const unsigned short* src = qkv + (size_t)b * T_LEN * QKV_N + 2 * C_DIM + h * DHEAD + d0;
    for (int i = 0; i < 32; i += 8)
        tile[ty + i][tx] = src[(size_t)(t0 + ty + i) * QKV_N + tx];
    __syncthreads();
    unsigned short* dst = vtg + ((size_t)bh * DHEAD + d0) * T_LEN + t0;
    for (int i = 0; i < 32; i += 8)
        dst[(size_t)(ty + i) * T_LEN + tx] = tile[tx][ty + i];
}

// ---------------- bf16 GEMM: A[M][K] x Bt[N][K] -> C[M][N] (+bias) ----------------
template<int BF16_OUT>
__global__ __launch_bounds__(256) void k_gemm(const unsigned short* __restrict__ A,
                       const unsigned short* __restrict__ Bt,
                       const float* __restrict__ bias,
                       void* __restrict__ C,
                       unsigned short* __restrict__ vtg,
                       int M, int N, int K) {
    __shared__ unsigned short As[128][64];   // linear, 128B rows
    __shared__ unsigned short Bs[128][64];

    const int tid  = threadIdx.x;
    const int lane = tid & 63;
    const int wv   = tid >> 6;
    const int wm = wv >> 1, wn = wv & 1;

    const int nwg = gridDim.x * gridDim.y;
    const int wg  = xcd_remap(blockIdx.y * gridDim.x + blockIdx.x, nwg);
    const int bx = wg % gridDim.x, by = wg / gridDim.x;
    const int m0 = by * 128;
    const int n0 = bx * 128;
    const int lr = lane & 15, lg = lane >> 4;

    f32x4 acc[4][4];
#pragma unroll
    for (int i = 0; i < 4; i++)
#pragma unroll
        for (int j = 0; j < 4; j++) acc[i][j] = (f32x4){0.f, 0.f, 0.f, 0.f};

    const int gr = lane >> 3;
    const int gc = 8 * ((lane & 7) ^ gr);

    for (int kt = 0; kt < K; kt += 64) {
        __syncthreads();
#pragma unroll
        for (int j = 0; j < 4; j++) {
            const int row = 32 * wv + 8 * j;
            GLL16(A  + (size_t)(m0 + row + gr) * K + kt + gc, &As[row][0]);
            GLL16(Bt + (size_t)(n0 + row + gr) * K + kt + gc, &Bs[row][0]);
        }
        __syncthreads();

#pragma unroll
        for (int s = 0; s < 2; s++) {
            const int cb = (s * 64 + lg * 16) ^ ((lr & 7) << 4);
            bf16x8 af[4], bfr[4];
#pragma unroll
            for (int i = 0; i < 4; i++)
                af[i] = as_bf16x8(*(const ushort8_t*)((const char*)&As[wm * 64 + i * 16 + lr][0] + cb));
#pragma unroll
            for (int j = 0; j < 4; j++)
                bfr[j] = as_bf16x8(*(const ushort8_t*)((const char*)&Bs[wn * 64 + j * 16 + lr][0] + cb));
#pragma unroll
            for (int i = 0; i < 4; i++)
#pragma unroll
                for (int j = 0; j < 4; j++)
                    acc[i][j] = mfma16(af[i], bfr[j], acc[i][j]);
        }
    }

    const bool isV = (vtg != nullptr) && (n0 >= 2 * C_DIM);
#pragma unroll
    for (int i = 0; i < 4; i++) {
#pragma unroll
        for (int j = 0; j < 4; j++) {
            const int col = n0 + wn * 64 + j * 16 + lr;
            const float bv = bias ? bias[col] : 0.f;
            if (isV) {
                const int dcol = col - 2 * C_DIM;
                const int hh = dcol >> 6, dd = dcol & 63;
                const int row0 = m0 + wm * 64 + i * 16 + lg * 4;
                const int bb = row0 >> 11, t0 = row0 & (T_LEN - 1);
                const unsigned int p0 = (unsigned int)f2bf(acc[i][j][0] + bv)
                                      | ((unsigned int)f2bf(acc[i][j][1] + bv) << 16);
                const unsigned int p1 = (unsigned int)f2bf(acc[i][j][2] + bv)
                                      | ((unsigned int)f2bf(acc[i][j][3] + bv) << 16);
                *(uint2*)&vtg[(((size_t)(bb * 16 + hh)) * 64 + dd) * T_LEN + t0] = make_uint2(p0, p1);
            } else {
#pragma unroll
                for (int r = 0; r < 4; r++) {
                    const int row = m0 + wm * 64 + i * 16 + lg * 4 + r;
                    const float v = acc[i][j][r] + bv;
                    if (BF16_OUT)
                        ((unsigned short*)C)[(size_t)row * N + col] = f2bf(v);
                    else
                        ((float*)C)[(size_t)row * N + col] = v;
                }
            }
        }
    }
}

// ---------------- flash attention (causal): barrier-free split-K waves ----------------
// Round = 64 keys. Wave w owns keys [kb+w*16, +16) x ALL 64 q: stages its own
// disjoint K rows (2 GLL) + V^T cols (2 GLL) into PER-WAVE double-buffered LDS;
// vmcnt(4) counted wait; ZERO block barriers in the round loop. Swapped QK^T
// gives S[key][q] (q=lane&15); PV A-operand (q=lr, k=lg*4+j) is the IDENTITY of
// what each lane holds -> no P transform at all (K=16 split, upper A half zero).
// O and l partials cross-wave reduced once per q-tile via LDS (region reused).
#define KS_OFF(W_, B_) ((W_) * 4096 + (B_) * 2048)
#define VS_OFF(W_, B_) (16384 + (W_) * 4096 + (B_) * 2048)
#define PART_OFF(W_)   ((W_) * 8704)
#define LBUF_OFF       34816
#define SCALE2 0.180336880f   // 0.125 * log2(e)
__global__ __launch_bounds__(256, 4) void k_attn(const unsigned short* __restrict__ qkv,
                                                 const unsigned short* __restrict__ vtg,
                                                 unsigned short* __restrict__ out) {
    __shared__ __align__(16) char smem[35840];
    float* smemf = (float*)smem;

    const int blk = xcd_remap(blockIdx.x, B_SZ * NHEAD * 16);
    const int pr = blk & 15;
    const int h  = (blk >> 4) & 15;
    const int b  = blk >> 8;
    const int bh = b * 16 + h;

    const int tid  = threadIdx.x;
    const int lane = tid & 63;
    const int w    = tid >> 6;
    const int lr = lane & 15, lg = lane >> 4;

    // K staging map (8 rows x 128B per GLL): row-in-8 = l>>3, pre-swizzled col
    const int gr = lane >> 3;
    const int gc = 8 * ((lane & 7) ^ gr);
    // V staging map (32 d-rows x 32B per GLL): d-in-32 = l>>1, 16B chunk xor
    const int vr = lane >> 1;
    const int vc = 8 * ((lane & 1) ^ ((lane >> 3) & 1));

    const size_t base = (size_t)b * T_LEN * QKV_N + (size_t)h * DHEAD;
    const unsigned short* Qp = qkv + base;
    const unsigned short* Kp = qkv + base + C_DIM;
    const unsigned short* Vt = vtg + (size_t)bh * DHEAD * T_LEN;

    int buf = 0;
    for (int t = 0; t < 2; t++) {
        const int qt = (t == 0) ? pr : (31 - pr);
        const int q0 = qt * 64;
        const int R  = qt + 1;

        // Q fragments: B-operand for all 4 q-subtiles (col q = fq*16+lr, k = ks*32+lg*8)
        bf16x8 qf[4][2];
#pragma unroll
        for (int fq = 0; fq < 4; fq++)
#pragma unroll
            for (int ks = 0; ks < 2; ks++)
                qf[fq][ks] = as_bf16x8(*(const ushort8_t*)
                    &Qp[(size_t)(q0 + fq * 16 + lr) * QKV_N + ks * 32 + lg * 8]);

        f32x4 o[4][4];
#pragma unroll
        for (int fq = 0; fq < 4; fq++)
#pragma unroll
            for (int fd = 0; fd < 4; fd++) o[fq][fd] = (f32x4){0.f, 0.f, 0.f, 0.f};
        float lp[4] = {0.f, 0.f, 0.f, 0.f};

        // prologue: stage round 0 (wave-private: K 16 rows, V^T 64d x 16 keys)
        {
            const int kw = w * 16;
            GLL16(Kp + (size_t)(kw + gr) * QKV_N + gc,         smem + KS_OFF(w, buf));
            GLL16(Kp + (size_t)(kw + 8 + gr) * QKV_N + gc,     smem + KS_OFF(w, buf) + 1024);
            GLL16(Vt + (size_t)vr * T_LEN + kw + vc,           smem + VS_OFF(w, buf));
            GLL16(Vt + (size_t)(32 + vr) * T_LEN + kw + vc,    smem + VS_OFF(w, buf) + 1024);
        }

        for (int r = 0; r < R; ++r) {
            const int kw = r * 64 + w * 16;      // this wave's key base

            if (r + 1 < R) {
                const int kn = kw + 64;
                GLL16(Kp + (size_t)(kn + gr) * QKV_N + gc,      smem + KS_OFF(w, buf ^ 1));
                GLL16(Kp + (size_t)(kn + 8 + gr) * QKV_N + gc,  smem + KS_OFF(w, buf ^ 1) + 1024);
                GLL16(Vt + (size_t)vr * T_LEN + kn + vc,        smem + VS_OFF(w, buf ^ 1));
                GLL16(Vt + (size_t)(32 + vr) * T_LEN + kn + vc, smem + VS_OFF(w, buf ^ 1) + 1024);
                asm volatile("s_waitcnt vmcnt(4)" ::: "memory");
            } else {
                asm volatile("s_waitcnt vmcnt(0)" ::: "memory");
            }
            __builtin_amdgcn_sched_barrier(0);

            // ---- V fragments early (b64, latency hides under QK^T+softmax) ----
            uint2 vb[4];
#pragma unroll
            for (int fd = 0; fd < 4; fd++) {
                const int d = fd * 16 + lr;
                vb[fd] = *(const uint2*)(smem + VS_OFF(w, buf) +
                         (d * 32 + ((lg * 8) ^ (((d >> 2) & 1) << 4))));
            }

            // ---- K fragments (A-operand: row=key-local=lr, k=d) ----
            bf16x8 kf[2];
#pragma unroll
            for (int ks = 0; ks < 2; ks++)
                kf[ks] = as_bf16x8(*(const ushort8_t*)(smem + KS_OFF(w, buf) +
                          lr * 128 + ((ks * 64 + lg * 16) ^ ((lr & 7) << 4))));

            // ---- swapped QK^T: S[key][q], key = lg*4+rr, q = fq*16+lr ----
            f32x4 s4[4];
            __builtin_amdgcn_s_setprio(1);
#pragma unroll
            for (int fq = 0; fq < 4; fq++) {
                f32x4 s = (f32x4){0.f, 0.f, 0.f, 0.f};
                s = mfma16(kf[0], qf[fq][0], s);
                s = mfma16(kf[1], qf[fq][1], s);
                s4[fq] = s;
            }
            __builtin_amdgcn_s_setprio(0);

            // ---- shift-free softmax + identity P-pack (no transform!) ----
            const bool last = (r == R - 1);
            bf16x8 pa[4];
#pragma unroll
            for (int fq = 0; fq < 4; fq++) {
                unsigned short hh[4];
#pragma unroll
                for (int rr = 0; rr < 4; rr++) {
                    float sv = fminf(s4[fq][rr] * SCALE2, 72.f);
                    if (last) {
                        const int kg = kw + lg * 4 + rr;
                        const int qg = q0 + fq * 16 + lr;
                        if (kg > qg) sv = -1e30f;
                    }
                    const float e = __builtin_amdgcn_exp2f(sv);
                    lp[fq] += e;
                    hh[rr] = __builtin_bit_cast(unsigned short, (__bf16)e);
                }
                uint4_t pw;
                pw.x = (unsigned int)hh[0] | ((unsigned int)hh[1] << 16);
                pw.y = (unsigned int)hh[2] | ((unsigned int)hh[3] << 16);
                pw.z = 0u;
                pw.w = 0u;   // upper A half = 0 (virtual keys)
                pa[fq] = __builtin_bit_cast(bf16x8, pw);
            }

            // ---- PV: K=16 via 16x16x32 with zeroed upper half ----
            __builtin_amdgcn_s_setprio(1);
#pragma unroll
            for (int fd = 0; fd < 4; fd++) {
                uint4_t bw;
                bw.x = vb[fd].x; bw.y = vb[fd].y;
                bw.z = vb[fd].x; bw.w = vb[fd].y;   // dup (finite) x A-zeros = 0
                const bf16x8 bv = __builtin_bit_cast(bf16x8, bw);
#pragma unroll
                for (int fq = 0; fq < 4; fq++)
                    o[fq][fd] = mfma16(pa[fq], bv, o[fq][fd]);
            }
            __builtin_amdgcn_s_setprio(0);
            buf ^= 1;
        }

        // ======== cross-wave reduction (once per q-tile) ========
        // lp: combine the 4 lg copies -> per-lane value for q = fq*16+lr
#pragma unroll
        for (int fq = 0; fq < 4; fq++) {
            lp[fq] += __shfl_xor(lp[fq], 16, 64);
            lp[fq] += __shfl_xor(lp[fq], 32, 64);
        }

        __syncthreads();   // all waves done with loop LDS; safe to reuse region

        if (lg == 0) {
#pragma unroll
            for (int fq = 0; fq < 4; fq++)
                *(float*)(smem + LBUF_OFF + (w * 64 + fq * 16 + lr) * 4) = lp[fq];
        }

#pragma unroll
        for (int half = 0; half < 2; half++) {
            // write this wave's O partials for q-half (fq = 2*half, 2*half+1)
#pragma unroll
            for (int f2 = 0; f2 < 2; f2++) {
                const int fq = half * 2 + f2;
#pragma unroll
                for (int fd = 0; fd < 4; fd++)
#pragma unroll
                    for (int rr = 0; rr < 4; rr++) {
                        const int ql = f2 * 16 + lg * 4 + rr;     // 0..31
                        smemf[(PART_OFF(w) >> 2) + ql * 68 + fd * 16 + lr] = o[fq][fd][rr];
                    }
            }
            __syncthreads();

            // reduce: wave w owns local q-rows [w*8, w*8+8) of this half
            {
                const int qrow = w * 8 + (lane >> 3);
                const int d0 = (lane & 7) * 8;
                f32x4 sA = (f32x4){0.f, 0.f, 0.f, 0.f};
                f32x4 sB = (f32x4){0.f, 0.f, 0.f, 0.f};
                float lt = 0.f;
#pragma unroll
                for (int pw = 0; pw < 4; pw++) {
                    const int fbase = (PART_OFF(pw) >> 2) + qrow * 68 + d0;
                    sA += *(const f32x4*)&smemf[fbase];
                    sB += *(const f32x4*)&smemf[fbase + 4];
                    lt += *(const float*)(smem + LBUF_OFF + (pw * 64 + half * 32 + qrow) * 4);
                }
                const float inv = 1.f / lt;
                ushort8_t ov;
#pragma unroll
                for (int j = 0; j < 4; j++) {
                    ov[j]     = f2bf(sA[j] * inv);
                    ov[4 + j] = f2bf(sB[j] * inv);
                }
                const int q = q0 + half * 32 + qrow;
                *(ushort8_t*)&out[((size_t)b * T_LEN + q) * C_DIM + h * DHEAD + d0] = ov;
            }
            __syncthreads();
        }
        // barriers above also drained stores (syncthreads waits vmcnt) before next tile
    }
}

// ---------------- launcher ----------------
extern "C" void kernel_launch(void* const* d_in, const int* in_sizes, int n_in,
                              void* d_out, int out_size, void* d_ws, size_t ws_size,
                              hipStream_t stream) {
    const float* x      = (const float*)d_in[0];
    const float* w_qkv  = (const float*)d_in[1];
    const float* b_qkv  = (const float*)d_in[2];
    const float* w_out  = (const float*)d_in[3];
    const float* b_out  = (const float*)d_in[4];
    float* out = (float*)d_out;

    char* ws = (char*)d_ws;
    unsigned short* xb    = (unsigned short*)(ws);                      // 16 MB (dead after QKV GEMM)
    unsigned short* wqkvT = (unsigned short*)(ws + 16777216);           //  6 MB
    unsigned short* woutT = (unsigned short*)(ws + 16777216 + 6291456); //  2 MB
    unsigned short* qkv   = (unsigned short*)(ws + 25165824);           // 48 MB
    unsigned short* attn  = (unsigned short*)(ws + 75497472);           // 16 MB

    const size_t VTG_OFF = 92274688ull;
    const bool fused_vt = (ws_size >= VTG_OFF + 16777216ull);
    unsigned short* vtg = fused_vt ? (unsigned short*)(ws + VTG_OFF)
                                   : (unsigned short*)(ws);  // xb region (dead after GEMM)

    {
        const int n4 = M_ROWS * C_DIM / 4;
        k_convert<<<(n4 + 255) / 256, 256, 0, stream>>>(x, xb, n4);
    }
    k_transpose_bf16<<<dim3(QKV_N / 32, C_DIM / 32), dim3(32, 8), 0, stream>>>(w_qkv, wqkvT, C_DIM, QKV_N);
    k_transpose_bf16<<<dim3(C_DIM / 32, C_DIM / 32), dim3(32, 8), 0, stream>>>(w_out, woutT, C_DIM, C_DIM);
    k_gemm<1><<<dim3(QKV_N / 128, M_ROWS / 128), 256, 0, stream>>>(
        xb, wqkvT, b_qkv, qkv, fused_vt ? vtg : nullptr, M_ROWS, QKV_N, C_DIM);
    if (!fused_vt)
        k_transpose_v<<<dim3(T_LEN / 32, 64 * 2), dim3(32, 8), 0, stream>>>(qkv, vtg);
    // barrier-free split-K causal attention
    k_attn<<<B_SZ * NHEAD * 16, 256, 0, stream>>>(qkv, vtg, attn);
    k_gemm<0><<<dim3(C_DIM / 128, M_ROWS / 128), 256, 0, stream>>>(
        attn, woutT, b_out, out, nullptr, M_ROWS, C_DIM, C_DIM);
}

// Round 12
// 172.949 us; speedup vs baseline: 2.1073x; 2.1073x over previous
//
#include <hip/hip_runtime.h>
#include <hip/hip_bf16.h>

// Problem constants
#define C_DIM  1024
#define NHEAD  16
#define DHEAD  64
#define T_LEN  2048
#define B_SZ   4
#define M_ROWS (B_SZ * T_LEN)   // 8192
#define QKV_N  (3 * C_DIM)      // 3072

typedef __bf16 bf16x8 __attribute__((ext_vector_type(8)));
typedef float  f32x4  __attribute__((ext_vector_type(4)));
typedef unsigned short ushort8_t __attribute__((ext_vector_type(8)));
typedef unsigned int   uint4_t   __attribute__((ext_vector_type(4)));

__device__ __forceinline__ unsigned short f2bf(float f) {
    union { float f; unsigned int u; } v; v.f = f;
    unsigned int r = v.u + 0x7FFFu + ((v.u >> 16) & 1u);
    return (unsigned short)(r >> 16);
}

__device__ __forceinline__ bf16x8 as_bf16x8(ushort8_t u) {
    return __builtin_bit_cast(bf16x8, u);
}

__device__ __forceinline__ f32x4 mfma16(bf16x8 a, bf16x8 b, f32x4 c) {
    return __builtin_amdgcn_mfma_f32_16x16x32_bf16(a, b, c, 0, 0, 0);
}

// async global->LDS, 16B per lane, dest = base + lane*16
#define GLL16(gsrc, ldst) __builtin_amdgcn_global_load_lds( \
    (const __attribute__((address_space(1))) void*)(gsrc),  \
    (__attribute__((address_space(3))) void*)(ldst), 16, 0, 0)

// bijective XCD-chunked remap (m204)
__device__ __forceinline__ int xcd_remap(int id, int nwg) {
    const int q = nwg >> 3, r = nwg & 7;
    const int xcd = id & 7, off = id >> 3;
    return (xcd < r) ? (xcd * (q + 1) + off) : (r * (q + 1) + (xcd - r) * q + off);
}

// ---------------- fp32 -> bf16 elementwise convert (vectorized) ----------------
__global__ void k_convert(const float* __restrict__ in, unsigned short* __restrict__ out, int n4) {
    int i = blockIdx.x * blockDim.x + threadIdx.x;
    if (i >= n4) return;
    const float4 v = ((const float4*)in)[i];
    unsigned int lo = (unsigned int)f2bf(v.x) | ((unsigned int)f2bf(v.y) << 16);
    unsigned int hi = (unsigned int)f2bf(v.z) | ((unsigned int)f2bf(v.w) << 16);
    ((uint2*)out)[i] = make_uint2(lo, hi);
}

// ---------------- fp32 [K][N] -> bf16 [N][K] tiled transpose ----------------
__global__ void k_transpose_bf16(const float* __restrict__ w, unsigned short* __restrict__ wT,
                                 int K, int N) {
    __shared__ float tile[32][33];
    const int n0 = blockIdx.x * 32, k0 = blockIdx.y * 32;
    const int tx = threadIdx.x, ty = threadIdx.y;  // 32 x 8
    for (int i = 0; i < 32; i += 8)
        tile[ty + i][tx] = w[(size_t)(k0 + ty + i) * N + (n0 + tx)];
    __syncthreads();
    for (int i = 0; i < 32; i += 8)
        wT[(size_t)(n0 + ty + i) * K + (k0 + tx)] = f2bf(tile[tx][ty + i]);
}

// ---------------- V -> V^T global pre-transpose (fallback if ws too small) ----------------
__global__ void k_transpose_v(const unsigned short* __restrict__ qkv,
                              unsigned short* __restrict__ vtg) {
    __shared__ unsigned short tile[32][33];
    const int tt = blockIdx.x;
    const int dy = blockIdx.y;
    const int bh = dy >> 1, dtile = dy & 1;
    const int b = bh >> 4, h = bh & 15;
    const int t0 = tt * 32, d0 = dtile * 32;
    const int tx = threadIdx.x, ty = threadIdx.y;  // 32 x 8
    const unsigned short* src = qkv + (size_t)b * T_LEN * QKV_N + 2 * C_DIM + h * DHEAD + d0;
    for (int i = 0; i < 32; i += 8)
        tile[ty + i][tx] = src[(size_t)(t0 + ty + i) * QKV_N + tx];
    __syncthreads();
    unsigned short* dst = vtg + ((size_t)bh * DHEAD + d0) * T_LEN + t0;
    for (int i = 0; i < 32; i += 8)
        dst[(size_t)(ty + i) * T_LEN + tx] = tile[tx][ty + i];
}

// ---------------- bf16 GEMM: A[M][K] x Bt[N][K] -> C[M][N] (+bias) ----------------
// 128x128 tile, BK=64, global_load_lds width-16 staging, XOR-swizzled LDS.
// If vtg != nullptr (QKV GEMM): V-column blocks (n0 >= 2048) write their tile
// TRANSPOSED to vtg[bh][d][t] instead of qkv (4 consecutive t packed per 8B store).
template<int BF16_OUT>
__global__ __launch_bounds__(256) void k_gemm(const unsigned short* __restrict__ A,
                       const unsigned short* __restrict__ Bt,
                       const float* __restrict__ bias,
                       void* __restrict__ C,
                       unsigned short* __restrict__ vtg,
                       int M, int N, int K) {
    __shared__ unsigned short As[128][64];   // linear, 128B rows
    __shared__ unsigned short Bs[128][64];

    const int tid  = threadIdx.x;
    const int lane = tid & 63;
    const int wv   = tid >> 6;
    const int wm = wv >> 1, wn = wv & 1;

    const int nwg = gridDim.x * gridDim.y;
    const int wg  = xcd_remap(blockIdx.y * gridDim.x + blockIdx.x, nwg);
    const int bx = wg % gridDim.x, by = wg / gridDim.x;
    const int m0 = by * 128;
    const int n0 = bx * 128;
    const int lr = lane & 15, lg = lane >> 4;

    f32x4 acc[4][4];
#pragma unroll
    for (int i = 0; i < 4; i++)
#pragma unroll
        for (int j = 0; j < 4; j++) acc[i][j] = (f32x4){0.f, 0.f, 0.f, 0.f};

    const int gr = lane >> 3;
    const int gc = 8 * ((lane & 7) ^ gr);

    for (int kt = 0; kt < K; kt += 64) {
        __syncthreads();
#pragma unroll
        for (int j = 0; j < 4; j++) {
            const int row = 32 * wv + 8 * j;
            GLL16(A  + (size_t)(m0 + row + gr) * K + kt + gc, &As[row][0]);
            GLL16(Bt + (size_t)(n0 + row + gr) * K + kt + gc, &Bs[row][0]);
        }
        __syncthreads();

#pragma unroll
        for (int s = 0; s < 2; s++) {
            const int cb = (s * 64 + lg * 16) ^ ((lr & 7) << 4);
            bf16x8 af[4], bfr[4];
#pragma unroll
            for (int i = 0; i < 4; i++)
                af[i] = as_bf16x8(*(const ushort8_t*)((const char*)&As[wm * 64 + i * 16 + lr][0] + cb));
#pragma unroll
            for (int j = 0; j < 4; j++)
                bfr[j] = as_bf16x8(*(const ushort8_t*)((const char*)&Bs[wn * 64 + j * 16 + lr][0] + cb));
#pragma unroll
            for (int i = 0; i < 4; i++)
#pragma unroll
                for (int j = 0; j < 4; j++)
                    acc[i][j] = mfma16(af[i], bfr[j], acc[i][j]);
        }
    }

    const bool isV = (vtg != nullptr) && (n0 >= 2 * C_DIM);
#pragma unroll
    for (int i = 0; i < 4; i++) {
#pragma unroll
        for (int j = 0; j < 4; j++) {
            const int col = n0 + wn * 64 + j * 16 + lr;
            const float bv = bias ? bias[col] : 0.f;
            if (isV) {
                // transposed write: vtg[bh][d][t], 4 consecutive t per lane
                const int dcol = col - 2 * C_DIM;          // 0..1023
                const int hh = dcol >> 6, dd = dcol & 63;
                const int row0 = m0 + wm * 64 + i * 16 + lg * 4;
                const int bb = row0 >> 11, t0 = row0 & (T_LEN - 1);
                const unsigned int p0 = (unsigned int)f2bf(acc[i][j][0] + bv)
                                      | ((unsigned int)f2bf(acc[i][j][1] + bv) << 16);
                const unsigned int p1 = (unsigned int)f2bf(acc[i][j][2] + bv)
                                      | ((unsigned int)f2bf(acc[i][j][3] + bv) << 16);
                *(uint2*)&vtg[(((size_t)(bb * 16 + hh)) * 64 + dd) * T_LEN + t0] = make_uint2(p0, p1);
            } else {
#pragma unroll
                for (int r = 0; r < 4; r++) {
                    const int row = m0 + wm * 64 + i * 16 + lg * 4 + r;
                    const float v = acc[i][j][r] + bv;
                    if (BF16_OUT)
                        ((unsigned short*)C)[(size_t)row * N + col] = f2bf(v);
                    else
                        ((float*)C)[(size_t)row * N + col] = v;
                }
            }
        }
    }
}

// ---------------- flash attention (causal): LDS-pipelined + swapped QK^T ----------------
// R9 structure with SINGLE barrier per round. Per-wave order:
//   vmcnt(0) [own GLLs for buf landed] -> s_barrier [all waves' buf complete]
//   -> issue GLLs for buf^1 [safe: buf^1 last read in round r-1, all waves past it]
//   -> compute from buf.
// Loads for round r+1 fly across the whole compute of round r.
#define KS_OFF(B_, ROW_) (((B_) << 13) + ((ROW_) << 7))
#define VS_OFF(B_, ROW_) (16384 + ((B_) << 13) + ((ROW_) << 7))
#define SCALE2 0.180336880f   // 0.125 * log2(e)
__global__ __launch_bounds__(256, 2) void k_attn(const unsigned short* __restrict__ qkv,
                                                 const unsigned short* __restrict__ vtg,
                                                 unsigned short* __restrict__ out) {
    __shared__ __align__(16) char smem[32768];

    const int blk = xcd_remap(blockIdx.x, B_SZ * NHEAD * 16);
    const int pr = blk & 15;
    const int h  = (blk >> 4) & 15;
    const int b  = blk >> 8;
    const int bh = b * 16 + h;

    const int tid  = threadIdx.x;
    const int lane = tid & 63;
    const int w    = tid >> 6;
    const int lr = lane & 15, lg = lane >> 4;
    const int gr = lane >> 3;                 // staging row within 8-row chunk
    const int gc = 8 * ((lane & 7) ^ gr);     // pre-swizzled source col (elems)
    const int ra = w * 16;                    // this wave's staging rows

    // bpermute lane indices for the P layout transform (R5-verified)
    const int sA = lr + 32 * (lg & 1);
    const int sB = sA + 16;
    const int fhi = lg >> 1;

    const size_t base = (size_t)b * T_LEN * QKV_N + (size_t)h * DHEAD;
    const unsigned short* Qp = qkv + base;
    const unsigned short* Kp = qkv + base + C_DIM;
    const unsigned short* Vt = vtg + (size_t)bh * DHEAD * T_LEN;

    int buf = 0;
    for (int t = 0; t < 2; t++) {
        const int qt = (t == 0) ? pr : (31 - pr);
        const int qw = qt * 64 + w * 16;
        const int qg = qw + lr;               // this lane's softmax q-row
        const int R  = qt + 1;

        bf16x8 qf[2];
#pragma unroll
        for (int s = 0; s < 2; s++)
            qf[s] = as_bf16x8(*(const ushort8_t*)&Qp[(size_t)(qw + lr) * QKV_N + s * 32 + lg * 8]);

        f32x4 o[4];
#pragma unroll
        for (int f = 0; f < 4; f++) o[f] = (f32x4){0.f, 0.f, 0.f, 0.f};
        float lp = 0.f;

        // prologue: stage round 0 into buf (4 GLL16 / wave, zero VGPRs)
        GLL16(Kp + (size_t)(ra + gr) * QKV_N + gc,          smem + KS_OFF(buf, ra));
        GLL16(Kp + (size_t)(ra + 8 + gr) * QKV_N + gc,      smem + KS_OFF(buf, ra + 8));
        GLL16(Vt + (size_t)(ra + gr) * T_LEN + gc,          smem + VS_OFF(buf, ra));
        GLL16(Vt + (size_t)(ra + 8 + gr) * T_LEN + gc,      smem + VS_OFF(buf, ra + 8));

        for (int r = 0; r < R; ++r) {
            const int kb = r * 64;

            // ---- single barrier: own loads drained, then all waves aligned ----
            asm volatile("s_waitcnt vmcnt(0)" ::: "memory");
            __builtin_amdgcn_s_barrier();
            __builtin_amdgcn_sched_barrier(0);   // no LDS read hoists above the barrier

            // ---- issue next round's loads NOW (fly across this round's compute) ----
            if (r + 1 < R) {
                const int kn = kb + 64;
                GLL16(Kp + (size_t)(kn + ra + gr) * QKV_N + gc,     smem + KS_OFF(buf ^ 1, ra));
                GLL16(Kp + (size_t)(kn + ra + 8 + gr) * QKV_N + gc, smem + KS_OFF(buf ^ 1, ra + 8));
                GLL16(Vt + (size_t)(ra + gr) * T_LEN + kn + gc,     smem + VS_OFF(buf ^ 1, ra));
                GLL16(Vt + (size_t)(ra + 8 + gr) * T_LEN + kn + gc, smem + VS_OFF(buf ^ 1, ra + 8));
            }

            // ---- swapped QK^T from Ks[buf]: S[key][q], q = lr ----
            f32x4 s4[4];
            __builtin_amdgcn_s_setprio(1);
#pragma unroll
            for (int f = 0; f < 4; f++) {
                const int row = f * 16 + lr;
                const bf16x8 kf0 = as_bf16x8(*(const ushort8_t*)
                    (smem + KS_OFF(buf, row) + ((lg * 16) ^ ((lr & 7) << 4))));
                const bf16x8 kf1 = as_bf16x8(*(const ushort8_t*)
                    (smem + KS_OFF(buf, row) + ((64 + lg * 16) ^ ((lr & 7) << 4))));
                f32x4 s = (f32x4){0.f, 0.f, 0.f, 0.f};
                s = mfma16(kf0, qf[0], s);
                s = mfma16(kf1, qf[1], s);
                s4[f] = s;
            }
            __builtin_amdgcn_s_setprio(0);

            // ---- shift-free softmax (exp2 domain), lane-local rows ----
            const bool last = (r == R - 1);
            unsigned int Dk[4][2];
#pragma unroll
            for (int f = 0; f < 4; f++) {
                unsigned short hh[4];
#pragma unroll
                for (int rr = 0; rr < 4; rr++) {
                    float sv = fminf(s4[f][rr] * SCALE2, 72.f);
                    if (last) {
                        const int kg = kb + f * 16 + lg * 4 + rr;
                        if (kg > qg) sv = -1e30f;
                    }
                    const float e = __builtin_amdgcn_exp2f(sv);
                    lp += e;
                    hh[rr] = __builtin_bit_cast(unsigned short, (__bf16)e);
                }
                Dk[f][0] = (unsigned int)hh[0] | ((unsigned int)hh[1] << 16);
                Dk[f][1] = (unsigned int)hh[2] | ((unsigned int)hh[3] << 16);
            }

            // ---- P transform (bpermute) + PV per 32-key window ----
#pragma unroll
            for (int st = 0; st < 2; st++) {
                const int a0 = __shfl((int)Dk[2 * st][0],     sA, 64);
                const int b0 = __shfl((int)Dk[2 * st + 1][0], sA, 64);
                const int a1 = __shfl((int)Dk[2 * st][1],     sA, 64);
                const int b1 = __shfl((int)Dk[2 * st + 1][1], sA, 64);
                const int a2 = __shfl((int)Dk[2 * st][0],     sB, 64);
                const int b2 = __shfl((int)Dk[2 * st + 1][0], sB, 64);
                const int a3 = __shfl((int)Dk[2 * st][1],     sB, 64);
                const int b3 = __shfl((int)Dk[2 * st + 1][1], sB, 64);
                uint4_t pw;
                pw.x = (unsigned int)(fhi ? b0 : a0);
                pw.y = (unsigned int)(fhi ? b1 : a1);
                pw.z = (unsigned int)(fhi ? b2 : a2);
                pw.w = (unsigned int)(fhi ? b3 : a3);
                const bf16x8 pa = __builtin_bit_cast(bf16x8, pw);

                __builtin_amdgcn_s_setprio(1);
#pragma unroll
                for (int f = 0; f < 4; f++) {
                    const int row = f * 16 + lr;
                    const bf16x8 bv = as_bf16x8(*(const ushort8_t*)
                        (smem + VS_OFF(buf, row) + ((st * 64 + lg * 16) ^ ((lr & 7) << 4))));
                    o[f] = mfma16(pa, bv, o[f]);
                }
                __builtin_amdgcn_s_setprio(0);
            }

            buf ^= 1;
        }

        // ---- l reduction: sum the 4 lg key-subsets for each q = lr ----
        lp += __shfl_xor(lp, 16, 64);
        lp += __shfl_xor(lp, 32, 64);

        // ---- normalize + store: o[f][rr] = O[q=qw+lg*4+rr][d=f*16+lr] ----
        float inv[4];
#pragma unroll
        for (int rr = 0; rr < 4; rr++)
            inv[rr] = 1.f / __shfl(lp, lg * 4 + rr, 64);
#pragma unroll
        for (int rr = 0; rr < 4; rr++) {
            const int q = qw + lg * 4 + rr;
#pragma unroll
            for (int f = 0; f < 4; f++)
                out[((size_t)b * T_LEN + q) * C_DIM + h * DHEAD + f * 16 + lr] =
                    f2bf(o[f][rr] * inv[rr]);
        }
    }
}

// ---------------- launcher ----------------
extern "C" void kernel_launch(void* const* d_in, const int* in_sizes, int n_in,
                              void* d_out, int out_size, void* d_ws, size_t ws_size,
                              hipStream_t stream) {
    const float* x      = (const float*)d_in[0];
    const float* w_qkv  = (const float*)d_in[1];
    const float* b_qkv  = (const float*)d_in[2];
    const float* w_out  = (const float*)d_in[3];
    const float* b_out  = (const float*)d_in[4];
    float* out = (float*)d_out;

    char* ws = (char*)d_ws;
    unsigned short* xb    = (unsigned short*)(ws);                      // 16 MB (dead after QKV GEMM)
    unsigned short* wqkvT = (unsigned short*)(ws + 16777216);           //  6 MB
    unsigned short* woutT = (unsigned short*)(ws + 16777216 + 6291456); //  2 MB
    unsigned short* qkv   = (unsigned short*)(ws + 25165824);           // 48 MB
    unsigned short* attn  = (unsigned short*)(ws + 75497472);           // 16 MB

    // vtg: prefer a dedicated region past 92 MB (lets QKV GEMM write V^T directly);
    // fall back to reusing xb + a separate transpose pass if ws is too small.
    const size_t VTG_OFF = 92274688ull;
    const bool fused_vt = (ws_size >= VTG_OFF + 16777216ull);
    unsigned short* vtg = fused_vt ? (unsigned short*)(ws + VTG_OFF)
                                   : (unsigned short*)(ws);  // xb region (dead after GEMM)

    {
        const int n4 = M_ROWS * C_DIM / 4;
        k_convert<<<(n4 + 255) / 256, 256, 0, stream>>>(x, xb, n4);
    }
    k_transpose_bf16<<<dim3(QKV_N / 32, C_DIM / 32), dim3(32, 8), 0, stream>>>(w_qkv, wqkvT, C_DIM, QKV_N);
    k_transpose_bf16<<<dim3(C_DIM / 32, C_DIM / 32), dim3(32, 8), 0, stream>>>(w_out, woutT, C_DIM, C_DIM);
    // QKV GEMM (consumes xb; V-blocks write vtg directly when fused)
    k_gemm<1><<<dim3(QKV_N / 128, M_ROWS / 128), 256, 0, stream>>>(
        xb, wqkvT, b_qkv, qkv, fused_vt ? vtg : nullptr, M_ROWS, QKV_N, C_DIM);
    if (!fused_vt)
        k_transpose_v<<<dim3(T_LEN / 32, 64 * 2), dim3(32, 8), 0, stream>>>(qkv, vtg);
    // causal attention (single-barrier LDS pipeline)
    k_attn<<<B_SZ * NHEAD * 16, 256, 0, stream>>>(qkv, vtg, attn);
    // output projection
    k_gemm<0><<<dim3(C_DIM / 128, M_ROWS / 128), 256, 0, stream>>>(
        attn, woutT, b_out, out, nullptr, M_ROWS, C_DIM, C_DIM);
}

// Round 13
// 169.510 us; speedup vs baseline: 2.1501x; 1.0203x over previous
//
#include <hip/hip_runtime.h>
#include <hip/hip_bf16.h>

// Problem constants
#define C_DIM  1024
#define NHEAD  16
#define DHEAD  64
#define T_LEN  2048
#define B_SZ   4
#define M_ROWS (B_SZ * T_LEN)   // 8192
#define QKV_N  (3 * C_DIM)      // 3072

typedef __bf16 bf16x8 __attribute__((ext_vector_type(8)));
typedef float  f32x4  __attribute__((ext_vector_type(4)));
typedef unsigned short ushort8_t __attribute__((ext_vector_type(8)));
typedef unsigned int   uint4_t   __attribute__((ext_vector_type(4)));
typedef short          short4_t  __attribute__((ext_vector_type(4)));

#if __has_builtin(__builtin_amdgcn_mfma_f32_16x16x16bf16_1k)
#define HAVE_MFMA_X16 1
#else
#define HAVE_MFMA_X16 0
#endif

__device__ __forceinline__ unsigned short f2bf(float f) {
    union { float f; unsigned int u; } v; v.f = f;
    unsigned int r = v.u + 0x7FFFu + ((v.u >> 16) & 1u);
    return (unsigned short)(r >> 16);
}

__device__ __forceinline__ bf16x8 as_bf16x8(ushort8_t u) {
    return __builtin_bit_cast(bf16x8, u);
}

__device__ __forceinline__ f32x4 mfma16(bf16x8 a, bf16x8 b, f32x4 c) {
    return __builtin_amdgcn_mfma_f32_16x16x32_bf16(a, b, c, 0, 0, 0);
}

// async global->LDS, 16B per lane, dest = base + lane*16
#define GLL16(gsrc, ldst) __builtin_amdgcn_global_load_lds( \
    (const __attribute__((address_space(1))) void*)(gsrc),  \
    (__attribute__((address_space(3))) void*)(ldst), 16, 0, 0)

// bijective XCD-chunked remap (m204)
__device__ __forceinline__ int xcd_remap(int id, int nwg) {
    const int q = nwg >> 3, r = nwg & 7;
    const int xcd = id & 7, off = id >> 3;
    return (xcd < r) ? (xcd * (q + 1) + off) : (r * (q + 1) + (xcd - r) * q + off);
}

// ---------------- fp32 -> bf16 elementwise convert (vectorized) ----------------
__global__ void k_convert(const float* __restrict__ in, unsigned short* __restrict__ out, int n4) {
    int i = blockIdx.x * blockDim.x + threadIdx.x;
    if (i >= n4) return;
    const float4 v = ((const float4*)in)[i];
    unsigned int lo = (unsigned int)f2bf(v.x) | ((unsigned int)f2bf(v.y) << 16);
    unsigned int hi = (unsigned int)f2bf(v.z) | ((unsigned int)f2bf(v.w) << 16);
    ((uint2*)out)[i] = make_uint2(lo, hi);
}

// ---------------- fp32 [K][N] -> bf16 [N][K] tiled transpose ----------------
__global__ void k_transpose_bf16(const float* __restrict__ w, unsigned short* __restrict__ wT,
                                 int K, int N) {
    __shared__ float tile[32][33];
    const int n0 = blockIdx.x * 32, k0 = blockIdx.y * 32;
    const int tx = threadIdx.x, ty = threadIdx.y;  // 32 x 8
    for (int i = 0; i < 32; i += 8)
        tile[ty + i][tx] = w[(size_t)(k0 + ty + i) * N + (n0 + tx)];
    __syncthreads();
    for (int i = 0; i < 32; i += 8)
        wT[(size_t)(n0 + ty + i) * K + (k0 + tx)] = f2bf(tile[tx][ty + i]);
}

// ---------------- V -> V^T global pre-transpose (fallback if ws too small) ----------------
__global__ void k_transpose_v(const unsigned short* __restrict__ qkv,
                              unsigned short* __restrict__ vtg) {
    __shared__ unsigned short tile[32][33];
    const int tt = blockIdx.x;
    const int dy = blockIdx.y;
    const int bh = dy >> 1, dtile = dy & 1;
    const int b = bh >> 4, h = bh & 15;
    const int t0 = tt * 32, d0 = dtile * 32;
    const int tx = threadIdx.x, ty = threadIdx.y;  // 32 x 8
    const unsigned short* src = qkv + (size_t)b * T_LEN * QKV_N + 2 * C_DIM + h * DHEAD + d0;
    for (int i = 0; i < 32; i += 8)
        tile[ty + i][tx] = src[(size_t)(t0 + ty + i) * QKV_N + tx];
    __syncthreads();
    unsigned short* dst = vtg + ((size_t)bh * DHEAD + d0) * T_LEN + t0;
    for (int i = 0; i < 32; i += 8)
        dst[(size_t)(ty + i) * T_LEN + tx] = tile[tx][ty + i];
}

// ---------------- bf16 GEMM: A[M][K] x Bt[N][K] -> C[M][N] (+bias) ----------------
// 128x128 tile, BK=64, global_load_lds width-16 staging, XOR-swizzled LDS.
// If vtg != nullptr (QKV GEMM): V-column blocks (n0 >= 2048) write their tile
// TRANSPOSED to vtg[bh][d][t] instead of qkv (4 consecutive t packed per 8B store).
template<int BF16_OUT>
__global__ __launch_bounds__(256) void k_gemm(const unsigned short* __restrict__ A,
                       const unsigned short* __restrict__ Bt,
                       const float* __restrict__ bias,
                       void* __restrict__ C,
                       unsigned short* __restrict__ vtg,
                       int M, int N, int K) {
    __shared__ unsigned short As[128][64];   // linear, 128B rows
    __shared__ unsigned short Bs[128][64];

    const int tid  = threadIdx.x;
    const int lane = tid & 63;
    const int wv   = tid >> 6;
    const int wm = wv >> 1, wn = wv & 1;

    const int nwg = gridDim.x * gridDim.y;
    const int wg  = xcd_remap(blockIdx.y * gridDim.x + blockIdx.x, nwg);
    const int bx = wg % gridDim.x, by = wg / gridDim.x;
    const int m0 = by * 128;
    const int n0 = bx * 128;
    const int lr = lane & 15, lg = lane >> 4;

    f32x4 acc[4][4];
#pragma unroll
    for (int i = 0; i < 4; i++)
#pragma unroll
        for (int j = 0; j < 4; j++) acc[i][j] = (f32x4){0.f, 0.f, 0.f, 0.f};

    const int gr = lane >> 3;
    const int gc = 8 * ((lane & 7) ^ gr);

    for (int kt = 0; kt < K; kt += 64) {
        __syncthreads();
#pragma unroll
        for (int j = 0; j < 4; j++) {
            const int row = 32 * wv + 8 * j;
            GLL16(A  + (size_t)(m0 + row + gr) * K + kt + gc, &As[row][0]);
            GLL16(Bt + (size_t)(n0 + row + gr) * K + kt + gc, &Bs[row][0]);
        }
        __syncthreads();

#pragma unroll
        for (int s = 0; s < 2; s++) {
            const int cb = (s * 64 + lg * 16) ^ ((lr & 7) << 4);
            bf16x8 af[4], bfr[4];
#pragma unroll
            for (int i = 0; i < 4; i++)
                af[i] = as_bf16x8(*(const ushort8_t*)((const char*)&As[wm * 64 + i * 16 + lr][0] + cb));
#pragma unroll
            for (int j = 0; j < 4; j++)
                bfr[j] = as_bf16x8(*(const ushort8_t*)((const char*)&Bs[wn * 64 + j * 16 + lr][0] + cb));
#pragma unroll
            for (int i = 0; i < 4; i++)
#pragma unroll
                for (int j = 0; j < 4; j++)
                    acc[i][j] = mfma16(af[i], bfr[j], acc[i][j]);
        }
    }

    const bool isV = (vtg != nullptr) && (n0 >= 2 * C_DIM);
#pragma unroll
    for (int i = 0; i < 4; i++) {
#pragma unroll
        for (int j = 0; j < 4; j++) {
            const int col = n0 + wn * 64 + j * 16 + lr;
            const float bv = bias ? bias[col] : 0.f;
            if (isV) {
                // transposed write: vtg[bh][d][t], 4 consecutive t per lane
                const int dcol = col - 2 * C_DIM;          // 0..1023
                const int hh = dcol >> 6, dd = dcol & 63;
                const int row0 = m0 + wm * 64 + i * 16 + lg * 4;
                const int bb = row0 >> 11, t0 = row0 & (T_LEN - 1);
                const unsigned int p0 = (unsigned int)f2bf(acc[i][j][0] + bv)
                                      | ((unsigned int)f2bf(acc[i][j][1] + bv) << 16);
                const unsigned int p1 = (unsigned int)f2bf(acc[i][j][2] + bv)
                                      | ((unsigned int)f2bf(acc[i][j][3] + bv) << 16);
                *(uint2*)&vtg[(((size_t)(bb * 16 + hh)) * 64 + dd) * T_LEN + t0] = make_uint2(p0, p1);
            } else {
#pragma unroll
                for (int r = 0; r < 4; r++) {
                    const int row = m0 + wm * 64 + i * 16 + lg * 4 + r;
                    const float v = acc[i][j][r] + bv;
                    if (BF16_OUT)
                        ((unsigned short*)C)[(size_t)row * N + col] = f2bf(v);
                    else
                        ((float*)C)[(size_t)row * N + col] = v;
                }
            }
        }
    }
}

// ---------------- flash attention (causal): register-direct PV (K=16 MFMA) ----------------
// R12 staging/barrier structure. Swapped QK^T gives S[key][q] with per-lane
// layout (q=lane&15, key=(lane>>4)*4+rr) == EXACTLY the B-operand layout of
// mfma_f32_16x16x16_bf16. So PV computes O^T[d][q] = V^T-frag(A) x P(B) with
// P fed straight from registers: zero bpermutes, zero P-LDS. V^T A-frags are
// 8B ds_read_b64. LDS traffic/wave/round: 24KB -> 20KB; DS instrs 36 -> 28.
#define KS_OFF(B_, ROW_) (((B_) << 13) + ((ROW_) << 7))
#define VS_OFF(B_, ROW_) (16384 + ((B_) << 13) + ((ROW_) << 7))
#define SCALE2 0.180336880f   // 0.125 * log2(e)
__global__ __launch_bounds__(256, 2) void k_attn(const unsigned short* __restrict__ qkv,
                                                 const unsigned short* __restrict__ vtg,
                                                 unsigned short* __restrict__ out) {
    __shared__ __align__(16) char smem[32768];

    const int blk = xcd_remap(blockIdx.x, B_SZ * NHEAD * 16);
    const int pr = blk & 15;
    const int h  = (blk >> 4) & 15;
    const int b  = blk >> 8;
    const int bh = b * 16 + h;

    const int tid  = threadIdx.x;
    const int lane = tid & 63;
    const int w    = tid >> 6;
    const int lr = lane & 15, lg = lane >> 4;
    const int gr = lane >> 3;                 // staging row within 8-row chunk
    const int gc = 8 * ((lane & 7) ^ gr);     // pre-swizzled source col (elems)
    const int ra = w * 16;                    // this wave's staging rows

    const size_t base = (size_t)b * T_LEN * QKV_N + (size_t)h * DHEAD;
    const unsigned short* Qp = qkv + base;
    const unsigned short* Kp = qkv + base + C_DIM;
    const unsigned short* Vt = vtg + (size_t)bh * DHEAD * T_LEN;

    int buf = 0;
    for (int t = 0; t < 2; t++) {
        const int qt = (t == 0) ? pr : (31 - pr);
        const int qw = qt * 64 + w * 16;
        const int qg = qw + lr;               // this lane's softmax q-row
        const int R  = qt + 1;

        bf16x8 qf[2];
#pragma unroll
        for (int s = 0; s < 2; s++)
            qf[s] = as_bf16x8(*(const ushort8_t*)&Qp[(size_t)(qw + lr) * QKV_N + s * 32 + lg * 8]);

        f32x4 o[4];   // o[fd][rr] = O^T[d = fd*16 + lg*4 + rr][q = lr]
#pragma unroll
        for (int f = 0; f < 4; f++) o[f] = (f32x4){0.f, 0.f, 0.f, 0.f};
        float lp = 0.f;

        // prologue: stage round 0 into buf (4 GLL16 / wave, zero VGPRs)
        GLL16(Kp + (size_t)(ra + gr) * QKV_N + gc,          smem + KS_OFF(buf, ra));
        GLL16(Kp + (size_t)(ra + 8 + gr) * QKV_N + gc,      smem + KS_OFF(buf, ra + 8));
        GLL16(Vt + (size_t)(ra + gr) * T_LEN + gc,          smem + VS_OFF(buf, ra));
        GLL16(Vt + (size_t)(ra + 8 + gr) * T_LEN + gc,      smem + VS_OFF(buf, ra + 8));

        for (int r = 0; r < R; ++r) {
            const int kb = r * 64;

            // ---- single barrier: own loads drained, then all waves aligned ----
            asm volatile("s_waitcnt vmcnt(0)" ::: "memory");
            __builtin_amdgcn_s_barrier();
            __builtin_amdgcn_sched_barrier(0);   // no LDS read hoists above the barrier

            // ---- issue next round's loads NOW (fly across this round's compute) ----
            if (r + 1 < R) {
                const int kn = kb + 64;
                GLL16(Kp + (size_t)(kn + ra + gr) * QKV_N + gc,     smem + KS_OFF(buf ^ 1, ra));
                GLL16(Kp + (size_t)(kn + ra + 8 + gr) * QKV_N + gc, smem + KS_OFF(buf ^ 1, ra + 8));
                GLL16(Vt + (size_t)(ra + gr) * T_LEN + kn + gc,     smem + VS_OFF(buf ^ 1, ra));
                GLL16(Vt + (size_t)(ra + 8 + gr) * T_LEN + kn + gc, smem + VS_OFF(buf ^ 1, ra + 8));
            }

            // ---- swapped QK^T from Ks[buf]: S[key][q], q = lr ----
            f32x4 s4[4];
            __builtin_amdgcn_s_setprio(1);
#pragma unroll
            for (int f = 0; f < 4; f++) {
                const int row = f * 16 + lr;
                const bf16x8 kf0 = as_bf16x8(*(const ushort8_t*)
                    (smem + KS_OFF(buf, row) + ((lg * 16) ^ ((lr & 7) << 4))));
                const bf16x8 kf1 = as_bf16x8(*(const ushort8_t*)
                    (smem + KS_OFF(buf, row) + ((64 + lg * 16) ^ ((lr & 7) << 4))));
                f32x4 s = (f32x4){0.f, 0.f, 0.f, 0.f};
                s = mfma16(kf0, qf[0], s);
                s = mfma16(kf1, qf[1], s);
                s4[f] = s;
            }
            __builtin_amdgcn_s_setprio(0);

            // ---- shift-free softmax (exp2 domain), lane-local; pack B-frags ----
            const bool last = (r == R - 1);
            unsigned int pb[4][2];   // pb[kg] = P keys kg*16+lg*4+{0..3}, col q=lr
#pragma unroll
            for (int f = 0; f < 4; f++) {
                unsigned short hh[4];
#pragma unroll
                for (int rr = 0; rr < 4; rr++) {
                    float sv = fminf(s4[f][rr] * SCALE2, 72.f);
                    if (last) {
                        const int kg = kb + f * 16 + lg * 4 + rr;
                        if (kg > qg) sv = -1e30f;
                    }
                    const float e = __builtin_amdgcn_exp2f(sv);
                    lp += e;
                    hh[rr] = __builtin_bit_cast(unsigned short, (__bf16)e);
                }
                pb[f][0] = (unsigned int)hh[0] | ((unsigned int)hh[1] << 16);
                pb[f][1] = (unsigned int)hh[2] | ((unsigned int)hh[3] << 16);
            }

            // ---- PV register-direct: O^T += V^T-frag x P, per 16-key group ----
            __builtin_amdgcn_s_setprio(1);
#pragma unroll
            for (int kg = 0; kg < 4; kg++) {
#if HAVE_MFMA_X16
                const short4_t pbv = __builtin_bit_cast(short4_t,
                    make_uint2(pb[kg][0], pb[kg][1]));
#else
                uint4_t pw;
                pw.x = pb[kg][0]; pw.y = pb[kg][1]; pw.z = 0u; pw.w = 0u;
                const bf16x8 pbv8 = __builtin_bit_cast(bf16x8, pw);
#endif
#pragma unroll
                for (int fd = 0; fd < 4; fd++) {
                    const int drow = fd * 16 + lr;
                    const uint2 va = *(const uint2*)(smem + VS_OFF(buf, drow) +
                                     ((kg * 32 + lg * 8) ^ ((lr & 7) << 4)));
#if HAVE_MFMA_X16
                    o[fd] = __builtin_amdgcn_mfma_f32_16x16x16bf16_1k(
                        __builtin_bit_cast(short4_t, va), pbv, o[fd], 0, 0, 0);
#else
                    uint4_t vw;
                    vw.x = va.x; vw.y = va.y; vw.z = va.x; vw.w = va.y;  // dup, B-zeros kill j>=4
                    o[fd] = mfma16(__builtin_bit_cast(bf16x8, vw), pbv8, o[fd]);
#endif
                }
            }
            __builtin_amdgcn_s_setprio(0);

            buf ^= 1;
        }

        // ---- l reduction: sum the 4 lg key-subsets for each q = lr ----
        lp += __shfl_xor(lp, 16, 64);
        lp += __shfl_xor(lp, 32, 64);
        const float inv = 1.f / lp;   // lane-local: lane's q IS lr

        // ---- store O^T: o[fd][rr] = O[q = qw+lr][d = fd*16 + lg*4 + rr] ----
#pragma unroll
        for (int fd = 0; fd < 4; fd++)
#pragma unroll
            for (int rr = 0; rr < 4; rr++) {
                const int d = fd * 16 + lg * 4 + rr;
                out[((size_t)b * T_LEN + qw + lr) * C_DIM + h * DHEAD + d] =
                    f2bf(o[fd][rr] * inv);
            }
    }
}

// ---------------- launcher ----------------
extern "C" void kernel_launch(void* const* d_in, const int* in_sizes, int n_in,
                              void* d_out, int out_size, void* d_ws, size_t ws_size,
                              hipStream_t stream) {
    const float* x      = (const float*)d_in[0];
    const float* w_qkv  = (const float*)d_in[1];
    const float* b_qkv  = (const float*)d_in[2];
    const float* w_out  = (const float*)d_in[3];
    const float* b_out  = (const float*)d_in[4];
    float* out = (float*)d_out;

    char* ws = (char*)d_ws;
    unsigned short* xb    = (unsigned short*)(ws);                      // 16 MB (dead after QKV GEMM)
    unsigned short* wqkvT = (unsigned short*)(ws + 16777216);           //  6 MB
    unsigned short* woutT = (unsigned short*)(ws + 16777216 + 6291456); //  2 MB
    unsigned short* qkv   = (unsigned short*)(ws + 25165824);           // 48 MB
    unsigned short* attn  = (unsigned short*)(ws + 75497472);           // 16 MB

    // vtg: prefer a dedicated region past 92 MB (lets QKV GEMM write V^T directly);
    // fall back to reusing xb + a separate transpose pass if ws is too small.
    const size_t VTG_OFF = 92274688ull;
    const bool fused_vt = (ws_size >= VTG_OFF + 16777216ull);
    unsigned short* vtg = fused_vt ? (unsigned short*)(ws + VTG_OFF)
                                   : (unsigned short*)(ws);  // xb region (dead after GEMM)

    {
        const int n4 = M_ROWS * C_DIM / 4;
        k_convert<<<(n4 + 255) / 256, 256, 0, stream>>>(x, xb, n4);
    }
    k_transpose_bf16<<<dim3(QKV_N / 32, C_DIM / 32), dim3(32, 8), 0, stream>>>(w_qkv, wqkvT, C_DIM, QKV_N);
    k_transpose_bf16<<<dim3(C_DIM / 32, C_DIM / 32), dim3(32, 8), 0, stream>>>(w_out, woutT, C_DIM, C_DIM);
    // QKV GEMM (consumes xb; V-blocks write vtg directly when fused)
    k_gemm<1><<<dim3(QKV_N / 128, M_ROWS / 128), 256, 0, stream>>>(
        xb, wqkvT, b_qkv, qkv, fused_vt ? vtg : nullptr, M_ROWS, QKV_N, C_DIM);
    if (!fused_vt)
        k_transpose_v<<<dim3(T_LEN / 32, 64 * 2), dim3(32, 8), 0, stream>>>(qkv, vtg);
    // causal attention (register-direct PV)
    k_attn<<<B_SZ * NHEAD * 16, 256, 0, stream>>>(qkv, vtg, attn);
    // output projection
    k_gemm<0><<<dim3(C_DIM / 128, M_ROWS / 128), 256, 0, stream>>>(
        attn, woutT, b_out, out, nullptr, M_ROWS, C_DIM, C_DIM);
}